// Round 25
// baseline (67.664 us; speedup 1.0000x reference)
//
#include <hip/hip_runtime.h>

// ---------------------------------------------------------------------------
// B=4, N1=1024, N2=1024, D=256, H=4, Dh=64
//   u[b,i,4] = gelu(prev@W_pre+b_pre) @ W_fuse[0:6]
//   v[b,j,4] = gelu(curr@W_cur+b_cur) @ W_fuse[6:12] + b_fuse
//   Gd_j[8] = gelu(d_j)@W_ffn[4:8] + gelu(e_j)@W_ffn[8:12] + b_ffn
//   logits = gelu(gelu(c)@W_ffn[0:4] + Gd_j)@W_fcc + b_fcc
//   softmax over i WITHOUT max-subtraction (masked -> w=0); plain-sum partials
//   res = P @ prev (per-head);  g_j = (T_j@W_ffn[0:4]+cnt*Gd_j)/(cnt+1)
//   out = res + gelu(g)@W_fcg + b_fcg
// Round-24 lesson: source-level B-prefetch was SUNK by the register
//   allocator (VGPR stayed 80 = fragments never lived across logit).
// Round-25: force it with asm volatile global_load_dwordx4, issued AFTER B1
//   (compiler drains vmcnt(0) before every s_barrier -> loads before B1
//   would be drained immediately). Explicit s_waitcnt vmcnt(0) after B2
//   (inline-asm loads are not in the compiler's waitcnt ledger).
// Round-23: single-buffer wA/sU + SPLIT=8 = best base (64.9us).
// Round-17: NO LDS-atomic compaction. Round-16: MFMA PV, w MUST be bf16.
// Round-9: exp once at w-write. Round-6: denominators PER (column, HEAD).
// Round-5: VGPR cliffs 64/128. Round-4: never cap min-waves.
// ---------------------------------------------------------------------------

using bf16x8 = __attribute__((ext_vector_type(8))) short;
using f32x4  = __attribute__((ext_vector_type(4))) float;
typedef float v2f __attribute__((ext_vector_type(2)));

__device__ __forceinline__ v2f pk_fma(v2f a, v2f b, v2f c){
    return __builtin_elementwise_fma(a, b, c);
}

// gelu(x) = x * rcp(1 + exp(-2*1.59576912*(x+0.044715x^3)))
__device__ __forceinline__ float gelu_f(float x){
    float x2 = x*x;
    float tt = x * __builtin_fmaf(0.044715f, x2, 1.0f);
    float e  = exp2f(-2.3022082f * tt);
    return x * __builtin_amdgcn_rcpf(1.0f + e);
}

__device__ __forceinline__ v2f gelu2(v2f x){
    v2f x2 = x*x;
    v2f tt = x * pk_fma((v2f){0.044715f,0.044715f}, x2, (v2f){1.0f,1.0f});
    float e0 = exp2f(-2.3022082f * tt[0]);
    float e1 = exp2f(-2.3022082f * tt[1]);
    v2f r = { __builtin_amdgcn_rcpf(1.0f + e0),
              __builtin_amdgcn_rcpf(1.0f + e1) };
    return x * r;
}

__device__ __forceinline__ unsigned short f2bf(float f){
    unsigned int u = __float_as_uint(f);
    u += 0x7FFFu + ((u >> 16) & 1u);                      // round-to-nearest
    return (unsigned short)(u >> 16);
}

// ---- kernel 1: fused per-row u/v (blocks 0..2047) + prevT (blocks 2048..2303)
__global__ __launch_bounds__(256) void k_rowsT(
    const float* __restrict__ prev, const float* __restrict__ curr,
    const float* __restrict__ W_pre, const float* __restrict__ b_pre,
    const float* __restrict__ W_cur, const float* __restrict__ b_cur,
    const float* __restrict__ W_fuse, const float* __restrict__ b_fuse,
    float* __restrict__ u_ws, float* __restrict__ v_ws,
    unsigned short* __restrict__ prevT)
{
    __shared__ float tile[64][65];
    int t = threadIdx.x;
    if (blockIdx.x < 2048){
        int gid  = blockIdx.x * 256 + t;
        int wave = gid >> 6;
        int lane = t & 63;
        bool isPrev = wave < 4096;
        int row = isPrev ? wave : (wave - 4096);
        const float* xrow = (isPrev ? prev : curr) + (size_t)row * 256;
        const float* W  = isPrev ? W_pre : W_cur;
        const float* bv = isPrev ? b_pre : b_cur;

        float4 x4 = *reinterpret_cast<const float4*>(xrow + lane*4);
        const float* Wl = W + lane*24;
        float p[6];
        #pragma unroll
        for (int k=0;k<6;++k)
            p[k] = x4.x*Wl[k] + x4.y*Wl[6+k] + x4.z*Wl[12+k] + x4.w*Wl[18+k];
        #pragma unroll
        for (int off=32; off>=1; off>>=1){
            #pragma unroll
            for (int k=0;k<6;++k) p[k] += __shfl_xor(p[k], off, 64);
        }
        if (lane == 0){
            float g[6];
            #pragma unroll
            for(int k=0;k<6;++k) g[k] = gelu_f(p[k] + bv[k]);
            int rb = isPrev ? 0 : 6;
            float o[4];
            #pragma unroll
            for(int kk=0;kk<4;++kk){
                float a = isPrev ? 0.0f : b_fuse[kk];
                #pragma unroll
                for(int k=0;k<6;++k) a += g[k]*W_fuse[(rb+k)*4+kk];
                o[kk]=a;
            }
            float* dst = (isPrev ? u_ws : v_ws) + (size_t)row*4;
            *reinterpret_cast<float4*>(dst) = make_float4(o[0],o[1],o[2],o[3]);
        }
    } else {
        int pbid = blockIdx.x - 2048;
        int b  = pbid >> 6;
        int it = (pbid >> 2) & 15;
        int dt = pbid & 3;
        int i0 = it*64, d0 = dt*64;
        int col = t & 63, rw = t >> 6;
        #pragma unroll
        for (int r = 0; r < 16; ++r){
            int row = rw + 4*r;
            tile[row][col] = prev[((size_t)b*1024 + i0 + row)*256 + d0 + col];
        }
        __syncthreads();
        #pragma unroll
        for (int r = 0; r < 16; ++r){
            int drow = rw + 4*r;
            prevT[((size_t)b*256 + d0 + drow)*1024 + i0 + col]
                = f2bf(tile[col][drow]);
        }
    }
}

// ---- kernel 2: per-column reductions over edges + Gd precompute ----
__global__ __launch_bounds__(256) void k_cols(
    const int* __restrict__ edges,
    const float* __restrict__ u_ws, const float* __restrict__ v_ws,
    const float* __restrict__ W_ffn, const float* __restrict__ b_ffn,
    float* __restrict__ Gd_ws, float* __restrict__ cnt_ws)
{
    int b  = blockIdx.x >> 6;
    int j0 = (blockIdx.x & 63) * 16;
    int t  = threadIdx.x;
    int jq = t & 3, sl = t >> 2;
    const int*   eb = edges + (size_t)b*1048576 + j0 + jq*4;
    const float* ub = u_ws + (size_t)b*4096;

    int   cnt[4] = {0,0,0,0};
    float S[4][4] = {{0.f}};
    float M[4][4];
    #pragma unroll
    for (int q=0;q<4;++q)
        #pragma unroll
        for (int k=0;k<4;++k) M[q][k] = -3.4e38f;

    #pragma unroll 4
    for (int ii=0; ii<16; ++ii){
        int i = sl*16 + ii;
        int4   e4 = *reinterpret_cast<const int4*>(eb + (size_t)i*1024);
        float4 u4 = *reinterpret_cast<const float4*>(ub + i*4);
        float uu[4] = {u4.x,u4.y,u4.z,u4.w};
        int   ee[4] = {e4.x,e4.y,e4.z,e4.w};
        #pragma unroll
        for (int q=0;q<4;++q){
            bool mk = ee[q]!=0;
            cnt[q] += mk ? 1 : 0;
            #pragma unroll
            for (int k=0;k<4;++k){
                S[q][k] += mk ? uu[k] : 0.0f;
                M[q][k]  = mk ? fmaxf(M[q][k],uu[k]) : M[q][k];
            }
        }
    }
    __shared__ float rS[64][16][4];
    __shared__ float rM[64][16][4];
    __shared__ int   rC[64][16];
    #pragma unroll
    for (int q=0;q<4;++q){
        int c = jq*4+q;
        #pragma unroll
        for (int k=0;k<4;++k){ rS[sl][c][k]=S[q][k]; rM[sl][c][k]=M[q][k]; }
        rC[sl][c]=cnt[q];
    }
    __syncthreads();
    float aS[4], aM[4]; int aC=0; int c2=0, hf=0;
    if (t < 128){
        c2 = t & 15; hf = t >> 4;
        #pragma unroll
        for(int k=0;k<4;++k){ aS[k]=0.f; aM[k]=-3.4e38f; }
        for (int s2=hf*8; s2<hf*8+8; ++s2){
            aC += rC[s2][c2];
            #pragma unroll
            for(int k=0;k<4;++k){ aS[k]+=rS[s2][c2][k]; aM[k]=fmaxf(aM[k],rM[s2][c2][k]); }
        }
    }
    __syncthreads();
    if (t < 128){
        rC[hf][c2]=aC;
        #pragma unroll
        for(int k=0;k<4;++k){ rS[hf][c2][k]=aS[k]; rM[hf][c2][k]=aM[k]; }
    }
    __syncthreads();
    if (t < 16){
        int cc=0; float Sa[4]={0,0,0,0};
        float Ma[4]={-3.4e38f,-3.4e38f,-3.4e38f,-3.4e38f};
        for (int s2=0;s2<8;++s2){
            cc += rC[s2][t];
            #pragma unroll
            for(int k=0;k<4;++k){ Sa[k]+=rS[s2][t][k]; Ma[k]=fmaxf(Ma[k],rM[s2][t][k]); }
        }
        size_t cj = (size_t)b*1024 + j0 + t;
        float4 v4 = *reinterpret_cast<const float4*>(v_ws + cj*4);
        float vv[4]={v4.x,v4.y,v4.z,v4.w};
        float cf = (float)cc, e1 = cf + 1.0f;
        float gd[4], ge[4];
        #pragma unroll
        for(int k=0;k<4;++k){
            float dk = (Sa[k] + cf*vv[k]) / e1;
            float ek;
            if (cc == 0) ek = 0.0f;
            else { float m1 = Ma[k]+vv[k]; ek = (cc < 1024) ? fmaxf(m1, 0.0f) : m1; }
            gd[k]=gelu_f(dk); ge[k]=gelu_f(ek);
        }
        #pragma unroll
        for(int kk=0;kk<8;++kk){
            float a = b_ffn[kk];
            #pragma unroll
            for(int k=0;k<4;++k)
                a += gd[k]*W_ffn[(4+k)*8+kk] + ge[k]*W_ffn[(8+k)*8+kk];
            Gd_ws[cj*8+kk]=a;
        }
        cnt_ws[cj]=cf;
    }
}

// ---- kernel 3: jtile=16, single-buffer wA/sU, asm-forced B-prefetch ----
// Block = (b, jtile of 16 cols, sp i-part). 256 threads, grid 4*64*SPLIT.
// Logit role: (il_w=t>>4 in 0..15, jl_w=t&15); rows il_w+16r, r=0..3.
// PV role: wave wv = head; 4 N-tiles x 2 K-steps + 2 ones-S MFMA.
// B-fragments loaded via asm volatile AFTER B1 (drain-safe placement);
// explicit s_waitcnt vmcnt(0) after B2 before first MFMA use.
template<int SPLIT>
__global__ __launch_bounds__(256) void k_main(
    const unsigned short* __restrict__ prevT, const int* __restrict__ edges,
    const float* __restrict__ u_ws, const float* __restrict__ v_ws,
    const float* __restrict__ Gd_ws,
    const float* __restrict__ W_ffn, const float* __restrict__ W_fcc,
    const float* __restrict__ b_fcc,
    float* __restrict__ Pws, float* __restrict__ Sws, float* __restrict__ Tws)
{
    const int RPB = 1024/SPLIT;
    int bid = blockIdx.x;
    int sp  = bid & (SPLIT-1);
    int jt  = (bid / SPLIT) & 63;
    int b   = bid / (SPLIT*64);
    int j0  = jt*16;
    int t   = threadIdx.x;
    int lane = t & 63;
    int wv   = t >> 6;
    int jl_w = t & 15, il_w = t >> 4;

    __shared__ unsigned short wA[4096];      // [h][row16][k64] bf16, swizzled
    __shared__ __align__(16) float sU[64][4];
    __shared__ float sV[16][4];
    __shared__ float sGd[16][8];

    if (t < 64)  (&sV[0][0])[t]  = v_ws[((size_t)b*1024 + j0)*4 + t];
    if (t < 128) (&sGd[0][0])[t] = Gd_ws[((size_t)b*1024 + j0)*8 + t];

    const float LOG2E = 1.4426950408889634f;
    v2f W4p[4][4], Wfcp[8][2], bfcp[2];
    #pragma unroll
    for(int k=0;k<4;++k)
        #pragma unroll
        for(int q=0;q<4;++q)
            W4p[k][q] = (v2f){W_ffn[k*8+2*q], W_ffn[k*8+2*q+1]};
    #pragma unroll
    for(int kk=0;kk<8;++kk)
        #pragma unroll
        for(int p2=0;p2<2;++p2)
            Wfcp[kk][p2] = (v2f){W_fcc[kk*4+2*p2]*LOG2E, W_fcc[kk*4+2*p2+1]*LOG2E};
    #pragma unroll
    for(int p2=0;p2<2;++p2)
        bfcp[p2] = (v2f){b_fcc[2*p2]*LOG2E, b_fcc[2*p2+1]*LOG2E};

    f32x4 accm[4];
    #pragma unroll
    for (int tile=0;tile<4;++tile) accm[tile] = (f32x4){0.f,0.f,0.f,0.f};
    f32x4 accs = (f32x4){0.f,0.f,0.f,0.f};
    bf16x8 onesB;
    #pragma unroll
    for (int e=0;e<8;++e) onesB[e] = (short)0x3F80;
    v2f Tp01 = {0,0}, Tp23 = {0,0};

    const int* ebase = edges + (size_t)b*1048576 + j0;
    const int NCH = RPB/64;
    const int base_i0 = sp*RPB;

    int arow = lane & 15, kgrp = lane >> 4;
    int aoff0 = (((wv*16 + arow)*64 + kgrp*8)*2) ^ ((arow & 7) << 4);
    int aoff1 = aoff0 ^ 64;
    const unsigned short* pTbase = prevT
        + ((size_t)b*256 + wv*64 + arow)*1024 + base_i0 + kgrp*8;

    // ---- prologue: load chunk0 sU + edges ----
    float su_r = u_ws[((size_t)b*1024 + base_i0)*4 + t];
    int egr[4];
    #pragma unroll
    for (int r=0;r<4;++r)
        egr[r] = ebase[(size_t)(base_i0 + il_w + 16*r)*1024 + jl_w];
    __syncthreads();                        // sV/sGd visible

    float4 v4p = *reinterpret_cast<const float4*>(&sV[jl_w][0]);
    float4 gd0 = *reinterpret_cast<const float4*>(&sGd[jl_w][0]);
    float4 gd1 = *reinterpret_cast<const float4*>(&sGd[jl_w][4]);

    for (int cc=0; cc<NCH; ++cc){
        (&sU[0][0])[t] = su_r;              // publish this chunk's sU
        __syncthreads();                    // B1: sU visible; prior PV done

        // ---- asm-forced B-fragment prefetch (AFTER B1; covered by logit) ----
        const unsigned short* pT = pTbase + (size_t)cc*64;
        bf16x8 b00, b01, b10, b11, b20, b21, b30, b31;
        asm volatile("global_load_dwordx4 %0, %1, off"
                     : "=v"(b00) : "v"(pT));
        asm volatile("global_load_dwordx4 %0, %1, off"
                     : "=v"(b01) : "v"(pT + 32));
        asm volatile("global_load_dwordx4 %0, %1, off"
                     : "=v"(b10) : "v"(pT + 16*1024));
        asm volatile("global_load_dwordx4 %0, %1, off"
                     : "=v"(b11) : "v"(pT + 16*1024 + 32));
        asm volatile("global_load_dwordx4 %0, %1, off"
                     : "=v"(b20) : "v"(pT + 32*1024));
        asm volatile("global_load_dwordx4 %0, %1, off"
                     : "=v"(b21) : "v"(pT + 32*1024 + 32));
        asm volatile("global_load_dwordx4 %0, %1, off"
                     : "=v"(b30) : "v"(pT + 48*1024));
        asm volatile("global_load_dwordx4 %0, %1, off"
                     : "=v"(b31) : "v"(pT + 48*1024 + 32));

        int eg_c[4] = {egr[0], egr[1], egr[2], egr[3]};
        {   // prefetch next chunk's sU + edges
            int i0n = base_i0 + ((cc+1 < NCH) ? (cc+1)*64 : 0);
            su_r = u_ws[((size_t)b*1024 + i0n)*4 + t];
            #pragma unroll
            for (int r=0;r<4;++r)
                egr[r] = ebase[(size_t)(i0n + il_w + 16*r)*1024 + jl_w];
        }

        // ---- logit phase: 4 rows per thread (independent chains) ----
        #pragma unroll
        for (int r=0;r<4;++r){
            int il = il_w + 16*r;
            int eg = eg_c[r];
            float4 u4 = *reinterpret_cast<const float4*>(&sU[il][0]);
            v2f g01 = gelu2((v2f){u4.x + v4p.x, u4.y + v4p.y});
            v2f g23 = gelu2((v2f){u4.z + v4p.z, u4.w + v4p.w});
            float m = eg ? 1.0f : 0.0f;
            v2f mm = {m, m};
            Tp01 = pk_fma(mm, g01, Tp01);
            Tp23 = pk_fma(mm, g23, Tp23);
            v2f a0 = {gd0.x, gd0.y}, a1 = {gd0.z, gd0.w};
            v2f a2 = {gd1.x, gd1.y}, a3 = {gd1.z, gd1.w};
            v2f G0 = {g01[0], g01[0]}, G1 = {g01[1], g01[1]};
            v2f G2 = {g23[0], g23[0]}, G3 = {g23[1], g23[1]};
            a0 = pk_fma(G0, W4p[0][0], a0); a1 = pk_fma(G0, W4p[0][1], a1);
            a2 = pk_fma(G0, W4p[0][2], a2); a3 = pk_fma(G0, W4p[0][3], a3);
            a0 = pk_fma(G1, W4p[1][0], a0); a1 = pk_fma(G1, W4p[1][1], a1);
            a2 = pk_fma(G1, W4p[1][2], a2); a3 = pk_fma(G1, W4p[1][3], a3);
            a0 = pk_fma(G2, W4p[2][0], a0); a1 = pk_fma(G2, W4p[2][1], a1);
            a2 = pk_fma(G2, W4p[2][2], a2); a3 = pk_fma(G2, W4p[2][3], a3);
            a0 = pk_fma(G3, W4p[3][0], a0); a1 = pk_fma(G3, W4p[3][1], a1);
            a2 = pk_fma(G3, W4p[3][2], a2); a3 = pk_fma(G3, W4p[3][3], a3);
            v2f f01 = gelu2(a0), f23 = gelu2(a1);
            v2f f45 = gelu2(a2), f67 = gelu2(a3);
            v2f L01 = bfcp[0], L23 = bfcp[1];
            float fv[8] = {f01[0],f01[1],f23[0],f23[1],f45[0],f45[1],f67[0],f67[1]};
            #pragma unroll
            for (int kk=0;kk<8;++kk){
                v2f F = {fv[kk], fv[kk]};
                L01 = pk_fma(F, Wfcp[kk][0], L01);
                L23 = pk_fma(F, Wfcp[kk][1], L23);
            }
            float lg[4] = {L01[0], L01[1], L23[0], L23[1]};
            int low = ((jl_w*64 + il)*2) ^ ((jl_w & 7) << 4);
            #pragma unroll
            for (int hh=0;hh<4;++hh){
                float wf = eg ? exp2f(lg[hh]) : 0.0f;
                *reinterpret_cast<unsigned short*>(
                    reinterpret_cast<char*>(wA) + hh*2048 + low) = f2bf(wf);
            }
        }
        __syncthreads();                    // B2: wA ready
        asm volatile("s_waitcnt vmcnt(0)"); // asm loads complete (safety)

        // ---- PV: pure MFMA on preloaded operands ----
        bf16x8 afr0 = *reinterpret_cast<const bf16x8*>(
            reinterpret_cast<const char*>(wA) + aoff0);
        bf16x8 afr1 = *reinterpret_cast<const bf16x8*>(
            reinterpret_cast<const char*>(wA) + aoff1);
        accm[0] = __builtin_amdgcn_mfma_f32_16x16x32_bf16(afr0, b00, accm[0], 0,0,0);
        accm[0] = __builtin_amdgcn_mfma_f32_16x16x32_bf16(afr1, b01, accm[0], 0,0,0);
        accm[1] = __builtin_amdgcn_mfma_f32_16x16x32_bf16(afr0, b10, accm[1], 0,0,0);
        accm[1] = __builtin_amdgcn_mfma_f32_16x16x32_bf16(afr1, b11, accm[1], 0,0,0);
        accm[2] = __builtin_amdgcn_mfma_f32_16x16x32_bf16(afr0, b20, accm[2], 0,0,0);
        accm[2] = __builtin_amdgcn_mfma_f32_16x16x32_bf16(afr1, b21, accm[2], 0,0,0);
        accm[3] = __builtin_amdgcn_mfma_f32_16x16x32_bf16(afr0, b30, accm[3], 0,0,0);
        accm[3] = __builtin_amdgcn_mfma_f32_16x16x32_bf16(afr1, b31, accm[3], 0,0,0);
        accs = __builtin_amdgcn_mfma_f32_16x16x32_bf16(afr0, onesB, accs, 0,0,0);
        accs = __builtin_amdgcn_mfma_f32_16x16x32_bf16(afr1, onesB, accs, 0,0,0);
    }

    size_t bp = ((size_t)b*64 + jt)*SPLIT + sp;

    // ---- tail: T reduction; sT4 aliases wA (barrier first: PV read wA) ----
    __syncthreads();
    float* sT4 = reinterpret_cast<float*>(wA);
    {
        float* ts = sT4 + (size_t)t*4;
        ts[0]=Tp01[0]; ts[1]=Tp01[1]; ts[2]=Tp23[0]; ts[3]=Tp23[1];
    }
    __syncthreads();
    if (t < 16){
        float T0=0,T1=0,T2=0,T3=0;
        for (int s2=0;s2<16;++s2){
            const float* p = sT4 + (size_t)(s2*16 + t)*4;
            T0+=p[0]; T1+=p[1]; T2+=p[2]; T3+=p[3];
        }
        float* td = Tws + (bp*16 + t)*4;
        td[0]=T0; td[1]=T1; td[2]=T2; td[3]=T3;
    }

    // ---- S from ones-MFMA; Pws epilogue (all 16 rows live) ----
    if (arow == 0){                           // lanes 0,16,32,48
        #pragma unroll
        for (int r2=0; r2<4; ++r2)
            Sws[bp*64 + wv*16 + kgrp*4 + r2] = accs[r2];
    }
    {
        #pragma unroll
        for (int tile=0; tile<4; ++tile){
            #pragma unroll
            for (int r2=0; r2<4; ++r2){
                int j   = kgrp*4 + r2;
                int dim = wv*64 + tile*16 + arow;
                Pws[((size_t)bp*16 + j)*256 + dim] = accm[tile][r2];
            }
        }
    }
}

// ---- kernel 4: merge split partials, normalize, add gelu(g)@W_fcg ----
// Block = (b, jt8 of 8 cols), grid 512; maps into jtile-16 partial layout.
template<int SPLIT>
__global__ __launch_bounds__(256) void k_merge(
    const float* __restrict__ Pws, const float* __restrict__ Sws,
    const float* __restrict__ Tws,
    const float* __restrict__ Gd_ws, const float* __restrict__ cnt_ws,
    const float* __restrict__ W_ffn, const float* __restrict__ W_fcg,
    const float* __restrict__ b_fcg, float* __restrict__ out)
{
    int b   = blockIdx.x >> 7;
    int jt8 = blockIdx.x & 127;
    int jt16 = jt8 >> 1;
    int cb  = (jt8 & 1) * 8;
    int j0  = jt8*8;
    int t  = threadIdx.x;
    int jl = t >> 5, hd = t & 31, h = hd >> 3, dq = hd & 7;
    int col = cb + jl;
    __shared__ float sG[8][8];

    size_t bp0 = ((size_t)b*64 + jt16)*SPLIT;
    float s = 0.0f, acc[8] = {0,0,0,0,0,0,0,0};
    #pragma unroll
    for (int sp2=0; sp2<SPLIT; ++sp2){
        const float* p = Pws + ((bp0+sp2)*16 + col)*256 + hd*8;
        float4 p0 = *reinterpret_cast<const float4*>(p);
        float4 p1 = *reinterpret_cast<const float4*>(p+4);
        acc[0]+=p0.x; acc[1]+=p0.y; acc[2]+=p0.z; acc[3]+=p0.w;
        acc[4]+=p1.x; acc[5]+=p1.y; acc[6]+=p1.z; acc[7]+=p1.w;
        s += Sws[(bp0+sp2)*64 + h*16 + col];
    }
    if (t < 8){
        float T[4] = {0,0,0,0};
        #pragma unroll
        for (int sp2=0; sp2<SPLIT; ++sp2){
            const float* tp = Tws + ((bp0+sp2)*16 + cb + t)*4;
            #pragma unroll
            for (int k=0;k<4;++k) T[k]+=tp[k];
        }
        size_t cj = (size_t)b*1024 + j0 + t;
        float cf = cnt_ws[cj];
        float inv = __fdividef(1.0f, cf + 1.0f);
        #pragma unroll
        for (int kk=0;kk<8;++kk){
            float a = cf*Gd_ws[cj*8+kk];
            #pragma unroll
            for (int k=0;k<4;++k) a += T[k]*W_ffn[k*8+kk];
            sG[t][kk] = gelu_f(a*inv);
        }
    }
    __syncthreads();

    float rs = (s > 0.0f) ? (1.0f/s) : 0.0f;
    int col0 = h*64 + dq*8;
    float gg[8];
    #pragma unroll
    for (int kk=0;kk<8;++kk) gg[kk]=sG[jl][kk];
    float o[8];
    #pragma unroll
    for (int d2=0;d2<8;++d2){
        float a = b_fcg[col0+d2];
        #pragma unroll
        for (int kk=0;kk<8;++kk) a += gg[kk]*W_fcg[kk*256 + col0 + d2];
        o[d2] = acc[d2]*rs + a;
    }
    float* ob = out + ((size_t)b*1024 + j0 + jl)*256 + col0;
    float4* o4 = reinterpret_cast<float4*>(ob);
    o4[0] = make_float4(o[0],o[1],o[2],o[3]);
    o4[1] = make_float4(o[4],o[5],o[6],o[7]);
}

extern "C" void kernel_launch(void* const* d_in, const int* in_sizes, int n_in,
                              void* d_out, int out_size, void* d_ws, size_t ws_size,
                              hipStream_t stream)
{
    const float* prev  = (const float*)d_in[0];
    const float* curr  = (const float*)d_in[1];
    const int*   edges = (const int*)  d_in[2];
    const float* W_pre = (const float*)d_in[3];
    const float* b_pre = (const float*)d_in[4];
    const float* W_cur = (const float*)d_in[5];
    const float* b_cur = (const float*)d_in[6];
    const float* W_fuse= (const float*)d_in[7];
    const float* b_fuse= (const float*)d_in[8];
    const float* W_ffn = (const float*)d_in[9];
    const float* b_ffn = (const float*)d_in[10];
    const float* W_fcc = (const float*)d_in[11];
    const float* b_fcc = (const float*)d_in[12];
    const float* W_fcg = (const float*)d_in[13];
    const float* b_fcg = (const float*)d_in[14];
    float* out = (float*)d_out;

    float* u_ws   = (float*)d_ws;          // 16384 floats
    float* v_ws   = u_ws  + 16384;         // 16384
    float* Gd_ws  = v_ws  + 16384;         // 32768
    float* cnt_ws = Gd_ws + 32768;         // 4096
    float* Pws    = cnt_ws + 4096;
    const size_t base_f = 16384 + 16384 + 32768 + 4096;

    // nblocks(SPLIT) = 256*SPLIT; Pws = nb*16*256, Sws = nb*64, Tws = nb*16*4
    const size_t p8  = (size_t)2048*16*256;       // 8,388,608 floats
    const size_t s8  = (size_t)2048*64;
    const size_t t8  = (size_t)2048*16*4;
    const size_t pT_f = (size_t)4*256*1024/2;     // 524,288 floats
    const size_t need8 = (base_f + p8 + s8 + t8 + pT_f) * 4;
    const size_t p4 = p8/2, s4v = s8/2, t4 = t8/2;
    const size_t need4 = (base_f + p4 + s4v + t4 + pT_f) * 4;
    const size_t p2 = p8/4, s2v = s8/4, t2 = t8/4;

    if (ws_size >= need8){
        float* Sws = Pws + p8;
        float* Tws = Sws + s8;
        unsigned short* prevT = (unsigned short*)(Tws + t8);
        k_rowsT<<<dim3(2304), dim3(256), 0, stream>>>(prev, curr, W_pre, b_pre,
            W_cur, b_cur, W_fuse, b_fuse, u_ws, v_ws, prevT);
        k_cols<<<dim3(256), dim3(256), 0, stream>>>(edges, u_ws, v_ws,
            W_ffn, b_ffn, Gd_ws, cnt_ws);
        k_main<8><<<dim3(2048), dim3(256), 0, stream>>>(prevT, edges, u_ws,
            v_ws, Gd_ws, W_ffn, W_fcc, b_fcc, Pws, Sws, Tws);
        k_merge<8><<<dim3(512), dim3(256), 0, stream>>>(Pws, Sws, Tws, Gd_ws,
            cnt_ws, W_ffn, W_fcg, b_fcg, out);
    } else if (ws_size >= need4){
        float* Sws = Pws + p4;
        float* Tws = Sws + s4v;
        unsigned short* prevT = (unsigned short*)(Tws + t4);
        k_rowsT<<<dim3(2304), dim3(256), 0, stream>>>(prev, curr, W_pre, b_pre,
            W_cur, b_cur, W_fuse, b_fuse, u_ws, v_ws, prevT);
        k_cols<<<dim3(256), dim3(256), 0, stream>>>(edges, u_ws, v_ws,
            W_ffn, b_ffn, Gd_ws, cnt_ws);
        k_main<4><<<dim3(1024), dim3(256), 0, stream>>>(prevT, edges, u_ws,
            v_ws, Gd_ws, W_ffn, W_fcc, b_fcc, Pws, Sws, Tws);
        k_merge<4><<<dim3(512), dim3(256), 0, stream>>>(Pws, Sws, Tws, Gd_ws,
            cnt_ws, W_ffn, W_fcg, b_fcg, out);
    } else {
        float* Sws = Pws + p2;
        float* Tws = Sws + s2v;
        unsigned short* prevT = (unsigned short*)(Tws + t2);
        k_rowsT<<<dim3(2304), dim3(256), 0, stream>>>(prev, curr, W_pre, b_pre,
            W_cur, b_cur, W_fuse, b_fuse, u_ws, v_ws, prevT);
        k_cols<<<dim3(256), dim3(256), 0, stream>>>(edges, u_ws, v_ws,
            W_ffn, b_ffn, Gd_ws, cnt_ws);
        k_main<2><<<dim3(512), dim3(256), 0, stream>>>(prevT, edges, u_ws,
            v_ws, Gd_ws, W_ffn, W_fcc, b_fcc, Pws, Sws, Tws);
        k_merge<2><<<dim3(512), dim3(256), 0, stream>>>(Pws, Sws, Tws, Gd_ws,
            cnt_ws, W_ffn, W_fcg, b_fcg, out);
    }
}

// Round 26
// 61.963 us; speedup vs baseline: 1.0920x; 1.0920x over previous
//
#include <hip/hip_runtime.h>

// ---------------------------------------------------------------------------
// B=4, N1=1024, N2=1024, D=256, H=4, Dh=64
//   u[b,i,4] = gelu(prev@W_pre+b_pre) @ W_fuse[0:6]
//   v[b,j,4] = gelu(curr@W_cur+b_cur) @ W_fuse[6:12] + b_fuse
//   Gd_j[8] = gelu(d_j)@W_ffn[4:8] + gelu(e_j)@W_ffn[8:12] + b_ffn
//   logits = gelu(gelu(c)@W_ffn[0:4] + Gd_j)@W_fcc + b_fcc
//   softmax over i WITHOUT max-subtraction (masked -> w=0); plain-sum partials
//   res = P @ prev (per-head);  g_j = (T_j@W_ffn[0:4]+cnt*Gd_j)/(cnt+1)
//   out = res + gelu(g)@W_fcg + b_fcg
// Round-25 lesson: asm-forced B-prefetch also neutral/negative (2nd attempt)
//   -> PV load latency is already hidden by wave overlap. Reverted.
// Round-26: round-23 base + bf16 Pws partials (they are plain sums of bf16
//   MFMA outputs anyway): halves the 33.8MB HBM round-trip of res partials.
// Round-23: single-buffer wA/sU + SPLIT=8 = best base (64.9us).
// Round-17: NO LDS-atomic compaction. Round-16: MFMA PV, w MUST be bf16.
// Round-9: exp once at w-write. Round-6: denominators PER (column, HEAD).
// Round-5: VGPR cliffs 64/128. Round-4: never cap min-waves.
// ---------------------------------------------------------------------------

using bf16x8 = __attribute__((ext_vector_type(8))) short;
using f32x4  = __attribute__((ext_vector_type(4))) float;
typedef float v2f __attribute__((ext_vector_type(2)));

__device__ __forceinline__ v2f pk_fma(v2f a, v2f b, v2f c){
    return __builtin_elementwise_fma(a, b, c);
}

// gelu(x) = x * rcp(1 + exp(-2*1.59576912*(x+0.044715x^3)))
__device__ __forceinline__ float gelu_f(float x){
    float x2 = x*x;
    float tt = x * __builtin_fmaf(0.044715f, x2, 1.0f);
    float e  = exp2f(-2.3022082f * tt);
    return x * __builtin_amdgcn_rcpf(1.0f + e);
}

__device__ __forceinline__ v2f gelu2(v2f x){
    v2f x2 = x*x;
    v2f tt = x * pk_fma((v2f){0.044715f,0.044715f}, x2, (v2f){1.0f,1.0f});
    float e0 = exp2f(-2.3022082f * tt[0]);
    float e1 = exp2f(-2.3022082f * tt[1]);
    v2f r = { __builtin_amdgcn_rcpf(1.0f + e0),
              __builtin_amdgcn_rcpf(1.0f + e1) };
    return x * r;
}

__device__ __forceinline__ unsigned short f2bf(float f){
    unsigned int u = __float_as_uint(f);
    u += 0x7FFFu + ((u >> 16) & 1u);                      // round-to-nearest
    return (unsigned short)(u >> 16);
}

__device__ __forceinline__ float bf2f(unsigned short s){
    return __uint_as_float(((unsigned int)s) << 16);
}

// ---- kernel 1: fused per-row u/v (blocks 0..2047) + prevT (blocks 2048..2303)
__global__ __launch_bounds__(256) void k_rowsT(
    const float* __restrict__ prev, const float* __restrict__ curr,
    const float* __restrict__ W_pre, const float* __restrict__ b_pre,
    const float* __restrict__ W_cur, const float* __restrict__ b_cur,
    const float* __restrict__ W_fuse, const float* __restrict__ b_fuse,
    float* __restrict__ u_ws, float* __restrict__ v_ws,
    unsigned short* __restrict__ prevT)
{
    __shared__ float tile[64][65];
    int t = threadIdx.x;
    if (blockIdx.x < 2048){
        int gid  = blockIdx.x * 256 + t;
        int wave = gid >> 6;
        int lane = t & 63;
        bool isPrev = wave < 4096;
        int row = isPrev ? wave : (wave - 4096);
        const float* xrow = (isPrev ? prev : curr) + (size_t)row * 256;
        const float* W  = isPrev ? W_pre : W_cur;
        const float* bv = isPrev ? b_pre : b_cur;

        float4 x4 = *reinterpret_cast<const float4*>(xrow + lane*4);
        const float* Wl = W + lane*24;
        float p[6];
        #pragma unroll
        for (int k=0;k<6;++k)
            p[k] = x4.x*Wl[k] + x4.y*Wl[6+k] + x4.z*Wl[12+k] + x4.w*Wl[18+k];
        #pragma unroll
        for (int off=32; off>=1; off>>=1){
            #pragma unroll
            for (int k=0;k<6;++k) p[k] += __shfl_xor(p[k], off, 64);
        }
        if (lane == 0){
            float g[6];
            #pragma unroll
            for(int k=0;k<6;++k) g[k] = gelu_f(p[k] + bv[k]);
            int rb = isPrev ? 0 : 6;
            float o[4];
            #pragma unroll
            for(int kk=0;kk<4;++kk){
                float a = isPrev ? 0.0f : b_fuse[kk];
                #pragma unroll
                for(int k=0;k<6;++k) a += g[k]*W_fuse[(rb+k)*4+kk];
                o[kk]=a;
            }
            float* dst = (isPrev ? u_ws : v_ws) + (size_t)row*4;
            *reinterpret_cast<float4*>(dst) = make_float4(o[0],o[1],o[2],o[3]);
        }
    } else {
        int pbid = blockIdx.x - 2048;
        int b  = pbid >> 6;
        int it = (pbid >> 2) & 15;
        int dt = pbid & 3;
        int i0 = it*64, d0 = dt*64;
        int col = t & 63, rw = t >> 6;
        #pragma unroll
        for (int r = 0; r < 16; ++r){
            int row = rw + 4*r;
            tile[row][col] = prev[((size_t)b*1024 + i0 + row)*256 + d0 + col];
        }
        __syncthreads();
        #pragma unroll
        for (int r = 0; r < 16; ++r){
            int drow = rw + 4*r;
            prevT[((size_t)b*256 + d0 + drow)*1024 + i0 + col]
                = f2bf(tile[col][drow]);
        }
    }
}

// ---- kernel 2: per-column reductions over edges + Gd precompute ----
__global__ __launch_bounds__(256) void k_cols(
    const int* __restrict__ edges,
    const float* __restrict__ u_ws, const float* __restrict__ v_ws,
    const float* __restrict__ W_ffn, const float* __restrict__ b_ffn,
    float* __restrict__ Gd_ws, float* __restrict__ cnt_ws)
{
    int b  = blockIdx.x >> 6;
    int j0 = (blockIdx.x & 63) * 16;
    int t  = threadIdx.x;
    int jq = t & 3, sl = t >> 2;
    const int*   eb = edges + (size_t)b*1048576 + j0 + jq*4;
    const float* ub = u_ws + (size_t)b*4096;

    int   cnt[4] = {0,0,0,0};
    float S[4][4] = {{0.f}};
    float M[4][4];
    #pragma unroll
    for (int q=0;q<4;++q)
        #pragma unroll
        for (int k=0;k<4;++k) M[q][k] = -3.4e38f;

    #pragma unroll 4
    for (int ii=0; ii<16; ++ii){
        int i = sl*16 + ii;
        int4   e4 = *reinterpret_cast<const int4*>(eb + (size_t)i*1024);
        float4 u4 = *reinterpret_cast<const float4*>(ub + i*4);
        float uu[4] = {u4.x,u4.y,u4.z,u4.w};
        int   ee[4] = {e4.x,e4.y,e4.z,e4.w};
        #pragma unroll
        for (int q=0;q<4;++q){
            bool mk = ee[q]!=0;
            cnt[q] += mk ? 1 : 0;
            #pragma unroll
            for (int k=0;k<4;++k){
                S[q][k] += mk ? uu[k] : 0.0f;
                M[q][k]  = mk ? fmaxf(M[q][k],uu[k]) : M[q][k];
            }
        }
    }
    __shared__ float rS[64][16][4];
    __shared__ float rM[64][16][4];
    __shared__ int   rC[64][16];
    #pragma unroll
    for (int q=0;q<4;++q){
        int c = jq*4+q;
        #pragma unroll
        for (int k=0;k<4;++k){ rS[sl][c][k]=S[q][k]; rM[sl][c][k]=M[q][k]; }
        rC[sl][c]=cnt[q];
    }
    __syncthreads();
    float aS[4], aM[4]; int aC=0; int c2=0, hf=0;
    if (t < 128){
        c2 = t & 15; hf = t >> 4;
        #pragma unroll
        for(int k=0;k<4;++k){ aS[k]=0.f; aM[k]=-3.4e38f; }
        for (int s2=hf*8; s2<hf*8+8; ++s2){
            aC += rC[s2][c2];
            #pragma unroll
            for(int k=0;k<4;++k){ aS[k]+=rS[s2][c2][k]; aM[k]=fmaxf(aM[k],rM[s2][c2][k]); }
        }
    }
    __syncthreads();
    if (t < 128){
        rC[hf][c2]=aC;
        #pragma unroll
        for(int k=0;k<4;++k){ rS[hf][c2][k]=aS[k]; rM[hf][c2][k]=aM[k]; }
    }
    __syncthreads();
    if (t < 16){
        int cc=0; float Sa[4]={0,0,0,0};
        float Ma[4]={-3.4e38f,-3.4e38f,-3.4e38f,-3.4e38f};
        for (int s2=0;s2<8;++s2){
            cc += rC[s2][t];
            #pragma unroll
            for(int k=0;k<4;++k){ Sa[k]+=rS[s2][t][k]; Ma[k]=fmaxf(Ma[k],rM[s2][t][k]); }
        }
        size_t cj = (size_t)b*1024 + j0 + t;
        float4 v4 = *reinterpret_cast<const float4*>(v_ws + cj*4);
        float vv[4]={v4.x,v4.y,v4.z,v4.w};
        float cf = (float)cc, e1 = cf + 1.0f;
        float gd[4], ge[4];
        #pragma unroll
        for(int k=0;k<4;++k){
            float dk = (Sa[k] + cf*vv[k]) / e1;
            float ek;
            if (cc == 0) ek = 0.0f;
            else { float m1 = Ma[k]+vv[k]; ek = (cc < 1024) ? fmaxf(m1, 0.0f) : m1; }
            gd[k]=gelu_f(dk); ge[k]=gelu_f(ek);
        }
        #pragma unroll
        for(int kk=0;kk<8;++kk){
            float a = b_ffn[kk];
            #pragma unroll
            for(int k=0;k<4;++k)
                a += gd[k]*W_ffn[(4+k)*8+kk] + ge[k]*W_ffn[(8+k)*8+kk];
            Gd_ws[cj*8+kk]=a;
        }
        cnt_ws[cj]=cf;
    }
}

// ---- kernel 3: jtile=16, single-buffer wA/sU, bf16 Pws partials ----
// Block = (b, jtile of 16 cols, sp i-part). 256 threads, grid 4*64*SPLIT.
// Logit role: (il_w=t>>4 in 0..15, jl_w=t&15); rows il_w+16r, r=0..3.
// PV role: wave wv = head; 4 N-tiles x 2 K-steps + 2 ones-S MFMA.
template<int SPLIT>
__global__ __launch_bounds__(256) void k_main(
    const unsigned short* __restrict__ prevT, const int* __restrict__ edges,
    const float* __restrict__ u_ws, const float* __restrict__ v_ws,
    const float* __restrict__ Gd_ws,
    const float* __restrict__ W_ffn, const float* __restrict__ W_fcc,
    const float* __restrict__ b_fcc,
    unsigned short* __restrict__ Pws, float* __restrict__ Sws,
    float* __restrict__ Tws)
{
    const int RPB = 1024/SPLIT;
    int bid = blockIdx.x;
    int sp  = bid & (SPLIT-1);
    int jt  = (bid / SPLIT) & 63;
    int b   = bid / (SPLIT*64);
    int j0  = jt*16;
    int t   = threadIdx.x;
    int lane = t & 63;
    int wv   = t >> 6;
    int jl_w = t & 15, il_w = t >> 4;

    __shared__ unsigned short wA[4096];      // [h][row16][k64] bf16, swizzled
    __shared__ __align__(16) float sU[64][4];
    __shared__ float sV[16][4];
    __shared__ float sGd[16][8];

    if (t < 64)  (&sV[0][0])[t]  = v_ws[((size_t)b*1024 + j0)*4 + t];
    if (t < 128) (&sGd[0][0])[t] = Gd_ws[((size_t)b*1024 + j0)*8 + t];

    const float LOG2E = 1.4426950408889634f;
    v2f W4p[4][4], Wfcp[8][2], bfcp[2];
    #pragma unroll
    for(int k=0;k<4;++k)
        #pragma unroll
        for(int q=0;q<4;++q)
            W4p[k][q] = (v2f){W_ffn[k*8+2*q], W_ffn[k*8+2*q+1]};
    #pragma unroll
    for(int kk=0;kk<8;++kk)
        #pragma unroll
        for(int p2=0;p2<2;++p2)
            Wfcp[kk][p2] = (v2f){W_fcc[kk*4+2*p2]*LOG2E, W_fcc[kk*4+2*p2+1]*LOG2E};
    #pragma unroll
    for(int p2=0;p2<2;++p2)
        bfcp[p2] = (v2f){b_fcc[2*p2]*LOG2E, b_fcc[2*p2+1]*LOG2E};

    f32x4 accm[4];
    #pragma unroll
    for (int tile=0;tile<4;++tile) accm[tile] = (f32x4){0.f,0.f,0.f,0.f};
    f32x4 accs = (f32x4){0.f,0.f,0.f,0.f};
    bf16x8 onesB;
    #pragma unroll
    for (int e=0;e<8;++e) onesB[e] = (short)0x3F80;
    v2f Tp01 = {0,0}, Tp23 = {0,0};

    const int* ebase = edges + (size_t)b*1048576 + j0;
    const int NCH = RPB/64;
    const int base_i0 = sp*RPB;

    int arow = lane & 15, kgrp = lane >> 4;
    int aoff0 = (((wv*16 + arow)*64 + kgrp*8)*2) ^ ((arow & 7) << 4);
    int aoff1 = aoff0 ^ 64;
    const unsigned short* pTbase = prevT
        + ((size_t)b*256 + wv*64 + arow)*1024 + base_i0 + kgrp*8;

    // ---- prologue: load chunk0 sU + edges ----
    float su_r = u_ws[((size_t)b*1024 + base_i0)*4 + t];
    int egr[4];
    #pragma unroll
    for (int r=0;r<4;++r)
        egr[r] = ebase[(size_t)(base_i0 + il_w + 16*r)*1024 + jl_w];
    __syncthreads();                        // sV/sGd visible

    float4 v4p = *reinterpret_cast<const float4*>(&sV[jl_w][0]);
    float4 gd0 = *reinterpret_cast<const float4*>(&sGd[jl_w][0]);
    float4 gd1 = *reinterpret_cast<const float4*>(&sGd[jl_w][4]);

    for (int cc=0; cc<NCH; ++cc){
        (&sU[0][0])[t] = su_r;              // publish this chunk's sU
        __syncthreads();                    // B1: sU visible; prior PV done

        int eg_c[4] = {egr[0], egr[1], egr[2], egr[3]};
        {   // prefetch next chunk's sU + edges (latency hidden under logit+PV)
            int i0n = base_i0 + ((cc+1 < NCH) ? (cc+1)*64 : 0);
            su_r = u_ws[((size_t)b*1024 + i0n)*4 + t];
            #pragma unroll
            for (int r=0;r<4;++r)
                egr[r] = ebase[(size_t)(i0n + il_w + 16*r)*1024 + jl_w];
        }

        // ---- logit phase: 4 rows per thread (independent chains) ----
        #pragma unroll
        for (int r=0;r<4;++r){
            int il = il_w + 16*r;
            int eg = eg_c[r];
            float4 u4 = *reinterpret_cast<const float4*>(&sU[il][0]);
            v2f g01 = gelu2((v2f){u4.x + v4p.x, u4.y + v4p.y});
            v2f g23 = gelu2((v2f){u4.z + v4p.z, u4.w + v4p.w});
            float m = eg ? 1.0f : 0.0f;
            v2f mm = {m, m};
            Tp01 = pk_fma(mm, g01, Tp01);
            Tp23 = pk_fma(mm, g23, Tp23);
            v2f a0 = {gd0.x, gd0.y}, a1 = {gd0.z, gd0.w};
            v2f a2 = {gd1.x, gd1.y}, a3 = {gd1.z, gd1.w};
            v2f G0 = {g01[0], g01[0]}, G1 = {g01[1], g01[1]};
            v2f G2 = {g23[0], g23[0]}, G3 = {g23[1], g23[1]};
            a0 = pk_fma(G0, W4p[0][0], a0); a1 = pk_fma(G0, W4p[0][1], a1);
            a2 = pk_fma(G0, W4p[0][2], a2); a3 = pk_fma(G0, W4p[0][3], a3);
            a0 = pk_fma(G1, W4p[1][0], a0); a1 = pk_fma(G1, W4p[1][1], a1);
            a2 = pk_fma(G1, W4p[1][2], a2); a3 = pk_fma(G1, W4p[1][3], a3);
            a0 = pk_fma(G2, W4p[2][0], a0); a1 = pk_fma(G2, W4p[2][1], a1);
            a2 = pk_fma(G2, W4p[2][2], a2); a3 = pk_fma(G2, W4p[2][3], a3);
            a0 = pk_fma(G3, W4p[3][0], a0); a1 = pk_fma(G3, W4p[3][1], a1);
            a2 = pk_fma(G3, W4p[3][2], a2); a3 = pk_fma(G3, W4p[3][3], a3);
            v2f f01 = gelu2(a0), f23 = gelu2(a1);
            v2f f45 = gelu2(a2), f67 = gelu2(a3);
            v2f L01 = bfcp[0], L23 = bfcp[1];
            float fv[8] = {f01[0],f01[1],f23[0],f23[1],f45[0],f45[1],f67[0],f67[1]};
            #pragma unroll
            for (int kk=0;kk<8;++kk){
                v2f F = {fv[kk], fv[kk]};
                L01 = pk_fma(F, Wfcp[kk][0], L01);
                L23 = pk_fma(F, Wfcp[kk][1], L23);
            }
            float lg[4] = {L01[0], L01[1], L23[0], L23[1]};
            int low = ((jl_w*64 + il)*2) ^ ((jl_w & 7) << 4);
            #pragma unroll
            for (int hh=0;hh<4;++hh){
                float wf = eg ? exp2f(lg[hh]) : 0.0f;
                *reinterpret_cast<unsigned short*>(
                    reinterpret_cast<char*>(wA) + hh*2048 + low) = f2bf(wf);
            }
        }
        __syncthreads();                    // B2: wA ready

        // ---- PV: 2 A-frags x (4 N-tiles + ones-S); 10 MFMA ----
        bf16x8 afr0 = *reinterpret_cast<const bf16x8*>(
            reinterpret_cast<const char*>(wA) + aoff0);
        bf16x8 afr1 = *reinterpret_cast<const bf16x8*>(
            reinterpret_cast<const char*>(wA) + aoff1);
        const unsigned short* pT = pTbase + (size_t)cc*64;
        #pragma unroll
        for (int tile=0; tile<4; ++tile){
            const unsigned short* pB = pT + (size_t)tile*16*1024;
            bf16x8 bfr0 = *reinterpret_cast<const bf16x8*>(pB);
            bf16x8 bfr1 = *reinterpret_cast<const bf16x8*>(pB + 32);
            accm[tile] = __builtin_amdgcn_mfma_f32_16x16x32_bf16(
                afr0, bfr0, accm[tile], 0, 0, 0);
            accm[tile] = __builtin_amdgcn_mfma_f32_16x16x32_bf16(
                afr1, bfr1, accm[tile], 0, 0, 0);
        }
        accs = __builtin_amdgcn_mfma_f32_16x16x32_bf16(afr0, onesB, accs, 0,0,0);
        accs = __builtin_amdgcn_mfma_f32_16x16x32_bf16(afr1, onesB, accs, 0,0,0);
    }

    size_t bp = ((size_t)b*64 + jt)*SPLIT + sp;

    // ---- tail: T reduction; sT4 aliases wA (barrier first: PV read wA) ----
    __syncthreads();
    float* sT4 = reinterpret_cast<float*>(wA);
    {
        float* ts = sT4 + (size_t)t*4;
        ts[0]=Tp01[0]; ts[1]=Tp01[1]; ts[2]=Tp23[0]; ts[3]=Tp23[1];
    }
    __syncthreads();
    if (t < 16){
        float T0=0,T1=0,T2=0,T3=0;
        for (int s2=0;s2<16;++s2){
            const float* p = sT4 + (size_t)(s2*16 + t)*4;
            T0+=p[0]; T1+=p[1]; T2+=p[2]; T3+=p[3];
        }
        float* td = Tws + (bp*16 + t)*4;
        td[0]=T0; td[1]=T1; td[2]=T2; td[3]=T3;
    }

    // ---- S from ones-MFMA; Pws epilogue (bf16, all 16 rows live) ----
    if (arow == 0){                           // lanes 0,16,32,48
        #pragma unroll
        for (int r2=0; r2<4; ++r2)
            Sws[bp*64 + wv*16 + kgrp*4 + r2] = accs[r2];
    }
    {
        #pragma unroll
        for (int tile=0; tile<4; ++tile){
            #pragma unroll
            for (int r2=0; r2<4; ++r2){
                int j   = kgrp*4 + r2;
                int dim = wv*64 + tile*16 + arow;
                Pws[((size_t)bp*16 + j)*256 + dim] = f2bf(accm[tile][r2]);
            }
        }
    }
}

// ---- kernel 4: merge split partials (bf16), normalize, add gelu(g)@W_fcg ----
// Block = (b, jt8 of 8 cols), grid 512; maps into jtile-16 partial layout.
template<int SPLIT>
__global__ __launch_bounds__(256) void k_merge(
    const unsigned short* __restrict__ Pws, const float* __restrict__ Sws,
    const float* __restrict__ Tws,
    const float* __restrict__ Gd_ws, const float* __restrict__ cnt_ws,
    const float* __restrict__ W_ffn, const float* __restrict__ W_fcg,
    const float* __restrict__ b_fcg, float* __restrict__ out)
{
    int b   = blockIdx.x >> 7;
    int jt8 = blockIdx.x & 127;
    int jt16 = jt8 >> 1;
    int cb  = (jt8 & 1) * 8;
    int j0  = jt8*8;
    int t  = threadIdx.x;
    int jl = t >> 5, hd = t & 31, h = hd >> 3, dq = hd & 7;
    int col = cb + jl;
    __shared__ float sG[8][8];

    size_t bp0 = ((size_t)b*64 + jt16)*SPLIT;
    float s = 0.0f, acc[8] = {0,0,0,0,0,0,0,0};
    #pragma unroll
    for (int sp2=0; sp2<SPLIT; ++sp2){
        const unsigned short* p = Pws + (((bp0+sp2)*16 + col)*256 + hd*8);
        bf16x8 pv = *reinterpret_cast<const bf16x8*>(p);
        #pragma unroll
        for (int k=0;k<8;++k)
            acc[k] += bf2f((unsigned short)pv[k]);
        s += Sws[(bp0+sp2)*64 + h*16 + col];
    }
    if (t < 8){
        float T[4] = {0,0,0,0};
        #pragma unroll
        for (int sp2=0; sp2<SPLIT; ++sp2){
            const float* tp = Tws + ((bp0+sp2)*16 + cb + t)*4;
            #pragma unroll
            for (int k=0;k<4;++k) T[k]+=tp[k];
        }
        size_t cj = (size_t)b*1024 + j0 + t;
        float cf = cnt_ws[cj];
        float inv = __fdividef(1.0f, cf + 1.0f);
        #pragma unroll
        for (int kk=0;kk<8;++kk){
            float a = cf*Gd_ws[cj*8+kk];
            #pragma unroll
            for (int k=0;k<4;++k) a += T[k]*W_ffn[k*8+kk];
            sG[t][kk] = gelu_f(a*inv);
        }
    }
    __syncthreads();

    float rs = (s > 0.0f) ? (1.0f/s) : 0.0f;
    int col0 = h*64 + dq*8;
    float gg[8];
    #pragma unroll
    for (int kk=0;kk<8;++kk) gg[kk]=sG[jl][kk];
    float o[8];
    #pragma unroll
    for (int d2=0;d2<8;++d2){
        float a = b_fcg[col0+d2];
        #pragma unroll
        for (int kk=0;kk<8;++kk) a += gg[kk]*W_fcg[kk*256 + col0 + d2];
        o[d2] = acc[d2]*rs + a;
    }
    float* ob = out + ((size_t)b*1024 + j0 + jl)*256 + col0;
    float4* o4 = reinterpret_cast<float4*>(ob);
    o4[0] = make_float4(o[0],o[1],o[2],o[3]);
    o4[1] = make_float4(o[4],o[5],o[6],o[7]);
}

extern "C" void kernel_launch(void* const* d_in, const int* in_sizes, int n_in,
                              void* d_out, int out_size, void* d_ws, size_t ws_size,
                              hipStream_t stream)
{
    const float* prev  = (const float*)d_in[0];
    const float* curr  = (const float*)d_in[1];
    const int*   edges = (const int*)  d_in[2];
    const float* W_pre = (const float*)d_in[3];
    const float* b_pre = (const float*)d_in[4];
    const float* W_cur = (const float*)d_in[5];
    const float* b_cur = (const float*)d_in[6];
    const float* W_fuse= (const float*)d_in[7];
    const float* b_fuse= (const float*)d_in[8];
    const float* W_ffn = (const float*)d_in[9];
    const float* b_ffn = (const float*)d_in[10];
    const float* W_fcc = (const float*)d_in[11];
    const float* b_fcc = (const float*)d_in[12];
    const float* W_fcg = (const float*)d_in[13];
    const float* b_fcg = (const float*)d_in[14];
    float* out = (float*)d_out;

    float* u_ws   = (float*)d_ws;          // 16384 floats
    float* v_ws   = u_ws  + 16384;         // 16384
    float* Gd_ws  = v_ws  + 16384;         // 32768
    float* cnt_ws = Gd_ws + 32768;         // 4096
    float* PwsF   = cnt_ws + 4096;         // bf16 region (ushort counts below)
    const size_t base_f = 16384 + 16384 + 32768 + 4096;

    // nblocks(SPLIT) = 256*SPLIT; Pws = nb*16*256 ushorts (nb*16*128 floats),
    // Sws = nb*64 floats, Tws = nb*16*4 floats, prevT = 1M ushorts.
    const size_t p8h = (size_t)2048*16*128;       // 4,194,304 floats
    const size_t s8  = (size_t)2048*64;
    const size_t t8  = (size_t)2048*16*4;
    const size_t pT_f = (size_t)4*256*1024/2;     // 524,288 floats
    const size_t need8 = (base_f + p8h + s8 + t8 + pT_f) * 4;
    const size_t p4h = p8h/2, s4v = s8/2, t4 = t8/2;
    const size_t need4 = (base_f + p4h + s4v + t4 + pT_f) * 4;
    const size_t p2h = p8h/4, s2v = s8/4, t2 = t8/4;

    if (ws_size >= need8){
        unsigned short* Pws = (unsigned short*)PwsF;
        float* Sws = PwsF + p8h;
        float* Tws = Sws + s8;
        unsigned short* prevT = (unsigned short*)(Tws + t8);
        k_rowsT<<<dim3(2304), dim3(256), 0, stream>>>(prev, curr, W_pre, b_pre,
            W_cur, b_cur, W_fuse, b_fuse, u_ws, v_ws, prevT);
        k_cols<<<dim3(256), dim3(256), 0, stream>>>(edges, u_ws, v_ws,
            W_ffn, b_ffn, Gd_ws, cnt_ws);
        k_main<8><<<dim3(2048), dim3(256), 0, stream>>>(prevT, edges, u_ws,
            v_ws, Gd_ws, W_ffn, W_fcc, b_fcc, Pws, Sws, Tws);
        k_merge<8><<<dim3(512), dim3(256), 0, stream>>>(Pws, Sws, Tws, Gd_ws,
            cnt_ws, W_ffn, W_fcg, b_fcg, out);
    } else if (ws_size >= need4){
        unsigned short* Pws = (unsigned short*)PwsF;
        float* Sws = PwsF + p4h;
        float* Tws = Sws + s4v;
        unsigned short* prevT = (unsigned short*)(Tws + t4);
        k_rowsT<<<dim3(2304), dim3(256), 0, stream>>>(prev, curr, W_pre, b_pre,
            W_cur, b_cur, W_fuse, b_fuse, u_ws, v_ws, prevT);
        k_cols<<<dim3(256), dim3(256), 0, stream>>>(edges, u_ws, v_ws,
            W_ffn, b_ffn, Gd_ws, cnt_ws);
        k_main<4><<<dim3(1024), dim3(256), 0, stream>>>(prevT, edges, u_ws,
            v_ws, Gd_ws, W_ffn, W_fcc, b_fcc, Pws, Sws, Tws);
        k_merge<4><<<dim3(512), dim3(256), 0, stream>>>(Pws, Sws, Tws, Gd_ws,
            cnt_ws, W_ffn, W_fcg, b_fcg, out);
    } else {
        unsigned short* Pws = (unsigned short*)PwsF;
        float* Sws = PwsF + p2h;
        float* Tws = Sws + s2v;
        unsigned short* prevT = (unsigned short*)(Tws + t2);
        k_rowsT<<<dim3(2304), dim3(256), 0, stream>>>(prev, curr, W_pre, b_pre,
            W_cur, b_cur, W_fuse, b_fuse, u_ws, v_ws, prevT);
        k_cols<<<dim3(256), dim3(256), 0, stream>>>(edges, u_ws, v_ws,
            W_ffn, b_ffn, Gd_ws, cnt_ws);
        k_main<2><<<dim3(512), dim3(256), 0, stream>>>(prevT, edges, u_ws,
            v_ws, Gd_ws, W_ffn, W_fcc, b_fcc, Pws, Sws, Tws);
        k_merge<2><<<dim3(512), dim3(256), 0, stream>>>(Pws, Sws, Tws, Gd_ws,
            cnt_ws, W_ffn, W_fcg, b_fcg, out);
    }
}